// Round 11
// baseline (310.030 us; speedup 1.0000x reference)
//
#include <hip/hip_runtime.h>

// Problem: VOCAB=10000, EMB=100, T=80, UNITS=256, BATCH=4096 — ALL FP32 I/O.
// out = sigmoid(h2_T);  h_l,t = tanh(x_l,t @ Wl + h_l,t-1 @ Ul + bl)
//
// v16 (3rd submit; rounds 9/10 died at CONTAINER ACQUISITION — pre-kernel,
// no compile/correctness signal; kernel audited clean for OOB/hangs).
// Theory from v15 counters: LDS data pipe dominates the iter
// (192 KB/CU-iter ~ 2260cy of 4650). State reads (128 KB) are irreducible
// at 8 waves, but the u2b stream (64 KB/CU-iter of LOOP-INVARIANT weights)
// doesn't belong on the LDS pipe: read it from global/L2 each iter (64 KB
// hot set, same lines every iter; VMEM pipe idle; lgkm-only barrier never
// drains vmcnt so these loads pipeline across iters). Chain loop split:
// x/yA (32 MFMAs, no ub dep) first to cover L2 latency; yB consumes ub
// after. u2s LDS buffer deleted. Rest identical to v15 (160-reg "+v" pin,
// lgkm barrier, P1 staging pipeline, rcp-tanh, compile-time buf indices).
// Tripwire: WRITE_SIZE must stay 4.1 MB (reg budget ~248/256 is the risk).
// Fallback rule: 3rd container failure => revert to verified v15 next round.
#define BATCH 4096
#define TLEN  80
#define EMBD  100
#define UNITS 256

typedef _Float16 f16;
typedef __attribute__((ext_vector_type(8))) _Float16 h8;   // 8 f16 = 4 VGPR MFMA A/B frag
typedef __attribute__((ext_vector_type(4))) float f32x4;   // MFMA C/D frag

// tanh(x) = sign(x) * (1-e)/(1+e), e = exp(-2|x|) in (0,1].
__device__ __forceinline__ float fast_tanh(float x) {
  float ax = __builtin_fabsf(x);
  float e  = __expf(-2.f * ax);
  float r  = (1.f - e) * __builtin_amdgcn_rcpf(1.f + e);
  return __builtin_copysignf(r, x);
}
// sigmoid(x) = rcp(1 + exp(-x)); saturates correctly at both ends.
__device__ __forceinline__ float fast_sigmoid(float x) {
  return __builtin_amdgcn_rcpf(1.f + __expf(-x));
}

// LDS-only barrier: all prior LDS ops visible, but vmcnt NOT drained —
// in-flight global loads (register-destined) cross the barrier.
__device__ __forceinline__ void block_sync_lds() {
  asm volatile("s_waitcnt lgkmcnt(0)\n\ts_barrier" ::: "memory");
}

// ---------------- workspace layout (5.58 MB <= 6.04 MB proven available) ---
// P1 table: 10000 x 256 f16 = 5,120,000 B.  wf frags: 458,752 B.
// B-frag layout (16x16x32, r7-verified): lane holds B[k=quad*8+j][n=lane&15].
// ktg slots: W1 = 0..3 (unused by main), U1 = 4..11, W2 = 12..19, U2 = 20..27.
#define KT_ALL 28
#define OFF_P1 ((size_t)0)
#define P1_BYTES ((size_t)10000 * UNITS * 2)                // 5,120,000
#define OFF_WF  P1_BYTES
#define WF_BYTES ((size_t)KT_ALL * 16 * 64 * 8 * 2)         //   458,752
#define WS_NEED (OFF_WF + WF_BYTES)                          // 5,578,752 B

__device__ __forceinline__ size_t fidx(int ktg, int nt, int lane) {
  return (((size_t)ktg * 16 + nt) * 64 + lane) * 8;
}

// ---------------- precompute: weights -> swizzled fp16 B-frags (r10-verified)
__global__ __launch_bounds__(256) void k_split_w16(
    const float* __restrict__ W1, const float* __restrict__ U1,
    const float* __restrict__ W2, const float* __restrict__ U2,
    f16* __restrict__ wf)
{
  int gid = blockIdx.x * 256 + threadIdx.x;           // one per (ktg,nt,lane)
  if (gid >= KT_ALL * 16 * 64) return;
  int lane = gid & 63, nt = (gid >> 6) & 15, ktg = gid >> 10;
  const float* M; int Kact, ktl;
  if (ktg < 4)       { M = W1; Kact = EMBD;  ktl = ktg;      }
  else if (ktg < 12) { M = U1; Kact = UNITS; ktl = ktg - 4;  }
  else if (ktg < 20) { M = W2; Kact = UNITS; ktl = ktg - 12; }
  else               { M = U2; Kact = UNITS; ktl = ktg - 20; }
  int n = nt * 16 + (lane & 15);
  int kb = ktl * 32 + (lane >> 4) * 8;
  size_t base = fidx(ktg, nt, lane);
#pragma unroll
  for (int j = 0; j < 8; ++j) {
    int k = kb + j;
    wf[base + j] = (f16)((k < Kact) ? M[(size_t)k * UNITS + n] : 0.f);  // RNE
  }
}

// ---------------- precompute: P1[v][n] = b1[n] + emb[v,:] @ W1 (f32 math) --
__global__ __launch_bounds__(256) void k_p1(
    const float* __restrict__ emb, const float* __restrict__ W1,
    const float* __restrict__ b1, f16* __restrict__ p1t)
{
  __shared__ float er[16][EMBD];
  const int v0 = blockIdx.x * 16;
  for (int i = threadIdx.x; i < 16 * EMBD; i += 256) {
    int vv = i / EMBD, kk = i - vv * EMBD;
    er[vv][kk] = emb[(size_t)(v0 + vv) * EMBD + kk];
  }
  __syncthreads();
  const int n = threadIdx.x;
  float acc[16];
  const float bb = b1[n];
#pragma unroll
  for (int vv = 0; vv < 16; ++vv) acc[vv] = bb;
  for (int k = 0; k < EMBD; ++k) {
    float w = W1[(size_t)k * UNITS + n];
#pragma unroll
    for (int vv = 0; vv < 16; ++vv) acc[vv] += er[vv][k] * w;
  }
#pragma unroll
  for (int vv = 0; vv < 16; ++vv)
    p1t[(size_t)(v0 + vv) * UNITS + n] = (f16)acc[vv];
}

#define MFMA16(A, B, C) __builtin_amdgcn_mfma_f32_16x16x32_f16(A, B, C, 0, 0, 0)

// store tanh result into next-step A-frag (single f16; layout r7-verified):
// elem (row=m, col=k): kt=col>>5, lane'=((col>>3)&3)*16+row, j'=col&7
__device__ __forceinline__ void store_frag1(f16* __restrict__ f, int col, int row, float v) {
  int a = (col >> 5) * 512 + (((col >> 3) & 3) * 16 + row) * 8 + (col & 7);
  f[a] = (f16)v;
}

#define P1S 264   // p1s row stride in f16: 528B = 132 dwords -> rows offset
                  // 4 banks; acc-init reads ~2-way max, writes conflict-free

// ---------------------------------------------------------------------------
// Main kernel v16: 512 thr = 8 waves (2/SIMD), wave w owns n-tiles 2w, 2w+1.
// Iter i: h1[i] = tanh(P1[i] + h1[i-1]@U1);  h2[i-1] = tanh(b2 + h1[i-1]@W2
// + h2[i-2]@U2).  One lgkm-only barrier/iter.  Buffer indices compile-time.
// Pinned: U1(a,b) W2(a,b) U2(a) = 160 regs.  U2(b): global/L2 (loop-
// invariant hot lines; VMEM pipe; loads pipeline across barriers).
// ---------------------------------------------------------------------------
__global__ __launch_bounds__(512, 2)
__attribute__((amdgpu_waves_per_eu(2, 2)))
void rnn_wsC(
    const int* __restrict__ idx, const f16* __restrict__ p1t,
    const f16* __restrict__ wf, const float* __restrict__ b2,
    float* __restrict__ out)
{
  __shared__ __align__(16) f16 f1[2][4096];      // [buf][kt*512 + lane*8 + j]
  __shared__ __align__(16) f16 f2[2][4096];
  __shared__ __align__(16) f16 p1s[2][16 * P1S]; // [buf][row*P1S + col]

  const int tid  = threadIdx.x;
  const int lane = tid & 63;
  const int w    = tid >> 6;          // wave 0..7 -> n-tiles 2w, 2w+1
  const int m    = lane & 15;
  const int q    = lane >> 4;
  const int b0   = blockIdx.x * 16;
  const int c0   = (2 * w) * 16 + m;
  const int c1   = (2 * w + 1) * 16 + m;

  const float b2a = b2[c0], b2b = b2[c1];

  // P1 staging assignment: thread covers 16B of row srow at offset spart*16B
  const int srow = tid >> 5, spart = tid & 31;
  const int* tokp = idx + (size_t)(b0 + srow) * TLEN;
  const f16* __restrict__ p1g = p1t + spart * 8;     // hoisted gather base
  // U2 odd-tile frag base for this (w, lane); frag kt at +kt*8192 f16
  const f16* __restrict__ u2g = wf + fidx(20, 2 * w + 1, lane);

  // -------- persistent weight fragments: U1(a,b), W2(a,b), U2(a) -----------
  h8 Bu1a[8], Bu1b[8], Bw2a[8], Bw2b[8], Bu2a[8];
#pragma unroll
  for (int kt = 0; kt < 8; ++kt) {
    Bu1a[kt] = *(const h8*)(wf + fidx(4 + kt, 2 * w, lane));
    Bu1b[kt] = *(const h8*)(wf + fidx(4 + kt, 2 * w + 1, lane));
    Bw2a[kt] = *(const h8*)(wf + fidx(12 + kt, 2 * w, lane));
    Bw2b[kt] = *(const h8*)(wf + fidx(12 + kt, 2 * w + 1, lane));
    Bu2a[kt] = *(const h8*)(wf + fidx(20 + kt, 2 * w, lane));
  }
  // pin ("+v", proven spill-free at exactly this 160-reg footprint)
#pragma unroll
  for (int kt = 0; kt < 8; ++kt) {
    asm volatile("" : "+v"(Bu1a[kt])); asm volatile("" : "+v"(Bu1b[kt]));
    asm volatile("" : "+v"(Bw2a[kt])); asm volatile("" : "+v"(Bw2b[kt]));
    asm volatile("" : "+v"(Bu2a[kt]));
  }

  // -------- zero h2[-1] state (f2[0]); f1[0] fully written by the peel -----
  for (int i = tid; i < 4096; i += 512) f2[0][i] = (f16)0.f;

  // -------- peel i=0: h1[0] = tanh(P1[0])  (one-time scalar gather) --------
#pragma unroll
  for (int r = 0; r < 4; ++r) {
    int row = q * 4 + r;
    int tk = idx[(size_t)(b0 + row) * TLEN + 0];
    const f16* pr = p1t + (size_t)tk * UNITS;
    store_frag1(f1[0], c0, row, fast_tanh((float)pr[c0]));
    store_frag1(f1[0], c1, row, fast_tanh((float)pr[c1]));
  }

  // -------- stage P1[1] into p1s[1]; prime token pipeline ------------------
  {
    int tk1 = tokp[1];
    h8 v = *(const h8*)(p1g + (size_t)tk1 * UNITS);
    *(h8*)&p1s[1][srow * P1S + spart * 8] = v;
  }
  int tkn = tokp[2];                   // token for iter1's stage of P1[2]
  __syncthreads();   // full barrier once: f2 zero, peel, p1s[1]

  // ======== one pipelined step; RD/WR are COMPILE-TIME 0/1 =================
  // Reads f1[RD], f2[RD], p1s[WR]; writes f1[WR], f2[WR], p1s[RD].
  // ub frags issued first (VMEM); x/yA chains (32 MFMAs, no ub dep) cover
  // their L2 latency; yB chain consumes them last.
#define RNN_STEP(RD, WR, STAGE, TKI)                                         \
  {                                                                          \
    h8 ub[8];                                                                \
    _Pragma("unroll")                                                        \
    for (int kt = 0; kt < 8; ++kt)                                           \
      ub[kt] = *(const h8*)(u2g + kt * 8192);                                \
    h8 p1v;                                                                  \
    if (STAGE) p1v = *(const h8*)(p1g + (size_t)tkn * UNITS);                \
    tkn = tokp[TKI];                                                         \
    f32x4 x0, x1;                                                            \
    _Pragma("unroll")                                                        \
    for (int r = 0; r < 4; ++r) {                                            \
      int row = q * 4 + r;                                                   \
      x0[r] = (float)p1s[WR][row * P1S + c0];                                \
      x1[r] = (float)p1s[WR][row * P1S + c1];                                \
    }                                                                        \
    f32x4 yA0 = (f32x4){b2a, b2a, b2a, b2a};                                 \
    f32x4 yA1 = (f32x4){b2b, b2b, b2b, b2b};                                 \
    f32x4 yB0 = (f32x4){0.f, 0.f, 0.f, 0.f};                                 \
    f32x4 yB1 = (f32x4){0.f, 0.f, 0.f, 0.f};                                 \
    _Pragma("unroll")                                                        \
    for (int kt = 0; kt < 8; ++kt) {                                         \
      h8 a1 = *(const h8*)&f1[RD][kt * 512 + lane * 8];                      \
      x0  = MFMA16(a1, Bu1a[kt], x0);                                        \
      x1  = MFMA16(a1, Bu1b[kt], x1);                                        \
      yA0 = MFMA16(a1, Bw2a[kt], yA0);                                       \
      yA1 = MFMA16(a1, Bw2b[kt], yA1);                                       \
    }                                                                        \
    _Pragma("unroll")                                                        \
    for (int kt = 0; kt < 8; ++kt) {                                         \
      h8 a2 = *(const h8*)&f2[RD][kt * 512 + lane * 8];                      \
      yB0 = MFMA16(a2, Bu2a[kt], yB0);                                       \
      yB1 = MFMA16(a2, ub[kt],   yB1);                                       \
    }                                                                        \
    _Pragma("unroll")                                                        \
    for (int r = 0; r < 4; ++r) {                                            \
      int row = q * 4 + r;                                                   \
      store_frag1(f1[WR], c0, row, fast_tanh(x0[r]));                        \
      store_frag1(f1[WR], c1, row, fast_tanh(x1[r]));                        \
      store_frag1(f2[WR], c0, row, fast_tanh(yA0[r] + yB0[r]));              \
      store_frag1(f2[WR], c1, row, fast_tanh(yA1[r] + yB1[r]));              \
    }                                                                        \
    if (STAGE) *(h8*)&p1s[RD][srow * P1S + spart * 8] = p1v;                 \
    block_sync_lds();                                                        \
  }

  // -------- main loop: 39 pairs cover i = 1..78; i = 79 peeled -------------
  for (int i = 1; i < TLEN - 1; i += 2) {
    int t2 = i + 3 < TLEN - 1 ? i + 3 : TLEN - 1;   // clamp (last pair only)
    RNN_STEP(0, 1, true, i + 2);    // i odd:  reads buf0, writes buf1
    RNN_STEP(1, 0, true, t2);       // i+1:    reads buf1, writes buf0
  }
  RNN_STEP(0, 1, false, TLEN - 1);  // i = 79: no staging (tkn load harmless)
#undef RNN_STEP

  // -------- tail: h2[79] = tanh(b2 + h1[79]@W2 + h2[78]@U2) -> out ---------
  {
    f32x4 yA0 = (f32x4){b2a, b2a, b2a, b2a};
    f32x4 yA1 = (f32x4){b2b, b2b, b2b, b2b};
    f32x4 yB0 = (f32x4){0.f, 0.f, 0.f, 0.f};
    f32x4 yB1 = (f32x4){0.f, 0.f, 0.f, 0.f};
#pragma unroll
    for (int kt = 0; kt < 8; ++kt) {
      h8 a1 = *(const h8*)&f1[1][kt * 512 + lane * 8];   // h1[79]
      h8 a2 = *(const h8*)&f2[1][kt * 512 + lane * 8];   // h2[78]
      h8 ub = *(const h8*)(u2g + kt * 8192);
      yA0 = MFMA16(a1, Bw2a[kt], yA0);
      yA1 = MFMA16(a1, Bw2b[kt], yA1);
      yB0 = MFMA16(a2, Bu2a[kt], yB0);
      yB1 = MFMA16(a2, ub,       yB1);
    }
#pragma unroll
    for (int r = 0; r < 4; ++r) {
      int row = q * 4 + r;
      out[(size_t)(b0 + row) * UNITS + c0] = fast_sigmoid(fast_tanh(yA0[r] + yB0[r]));
      out[(size_t)(b0 + row) * UNITS + c1] = fast_sigmoid(fast_tanh(yA1[r] + yB1[r]));
    }
  }
}

// ---------------------------------------------------------------------------
extern "C" void kernel_launch(void* const* d_in, const int* in_sizes, int n_in,
                              void* d_out, int out_size, void* d_ws, size_t ws_size,
                              hipStream_t stream)
{
  const int*   idx = (const int*)d_in[0];
  const float* emb = (const float*)d_in[1];
  const float* W1  = (const float*)d_in[2];
  const float* U1  = (const float*)d_in[3];
  const float* b1  = (const float*)d_in[4];
  const float* W2  = (const float*)d_in[5];
  const float* U2  = (const float*)d_in[6];
  const float* b2  = (const float*)d_in[7];
  // d_in[8] (Wd), d_in[9] (bd) dead in the reference output.
  float* out = (float*)d_out;

  f16* p1t = (f16*)((char*)d_ws + OFF_P1);
  f16* wf  = (f16*)((char*)d_ws + OFF_WF);
  k_p1<<<10000 / 16, 256, 0, stream>>>(emb, W1, b1, p1t);
  k_split_w16<<<(KT_ALL * 16 * 64 + 255) / 256, 256, 0, stream>>>(W1, U1, W2, U2, wf);
  rnn_wsC<<<BATCH / 16, 512, 0, stream>>>(idx, p1t, wf, b2, out);
}

// Round 12
// 216.371 us; speedup vs baseline: 1.4329x; 1.4329x over previous
//
#include <hip/hip_runtime.h>

// Problem: VOCAB=10000, EMB=100, T=80, UNITS=256, BATCH=4096 — ALL FP32 I/O.
// out = sigmoid(h2_T);  h_l,t = tanh(x_l,t @ Wl + h_l,t-1 @ Ul + bl)
//
// v17 theory (from v16 counters): v16's u2b-from-global overflowed the reg
// budget (WRITE 18MB spills) -> revert to verified v15 structure (153us) and
// cut the LDS pipe (3400 of 4600 cy/iter) by INSTRUCTION COUNT instead:
// swapped-operand MFMA. W's B-frag bytes == W^T's A-frag bytes, and h's
// A-frag bytes == h^T's B-frag bytes, so MFMA16(Wfrag, hfrag, acc) computes
// (h@W)^T with ZERO data-layout changes. Lane then holds 4 CONSECUTIVE n
// for one batch row ->
//  - epilogue: 16 ds_write_b16 -> 4 ds_write_b64
//  - P1 acc-init: 8 ds_read_u16 -> 2 ds_read_b64
//  - out: 8 scalar stores -> 2 global_store_dwordx4
// LDS instr/wave/iter 49 -> 31. Everything else (160-reg "+v" pin, u2b in
// 64KB dynamic LDS, lgkm-only barrier, P1 b128 staging, rcp-tanh,
// compile-time buffer indices) byte-identical to v15.
// Tripwire: WRITE_SIZE must stay 4.1 MB.
#define BATCH 4096
#define TLEN  80
#define EMBD  100
#define UNITS 256

typedef _Float16 f16;
typedef __attribute__((ext_vector_type(8))) _Float16 h8;   // 8 f16 = 4 VGPR MFMA A/B frag
typedef __attribute__((ext_vector_type(4))) _Float16 h4;   // 4 f16 = b64
typedef __attribute__((ext_vector_type(4))) float f32x4;   // MFMA C/D frag

// tanh(x) = sign(x) * (1-e)/(1+e), e = exp(-2|x|) in (0,1].
__device__ __forceinline__ float fast_tanh(float x) {
  float ax = __builtin_fabsf(x);
  float e  = __expf(-2.f * ax);
  float r  = (1.f - e) * __builtin_amdgcn_rcpf(1.f + e);
  return __builtin_copysignf(r, x);
}
// sigmoid(x) = rcp(1 + exp(-x)); saturates correctly at both ends.
__device__ __forceinline__ float fast_sigmoid(float x) {
  return __builtin_amdgcn_rcpf(1.f + __expf(-x));
}

// LDS-only barrier: all prior LDS ops visible, but vmcnt NOT drained.
__device__ __forceinline__ void block_sync_lds() {
  asm volatile("s_waitcnt lgkmcnt(0)\n\ts_barrier" ::: "memory");
}

// ---------------- workspace layout (5.58 MB <= 6.04 MB proven available) ---
// P1 table: 10000 x 256 f16 = 5,120,000 B.  wf frags: 458,752 B.
// B-frag layout (16x16x32, r7-verified): lane holds B[k=quad*8+j][n=lane&15].
// ktg slots: W1 = 0..3 (unused by main), U1 = 4..11, W2 = 12..19, U2 = 20..27.
#define KT_ALL 28
#define OFF_P1 ((size_t)0)
#define P1_BYTES ((size_t)10000 * UNITS * 2)                // 5,120,000
#define OFF_WF  P1_BYTES
#define WF_BYTES ((size_t)KT_ALL * 16 * 64 * 8 * 2)         //   458,752
#define WS_NEED (OFF_WF + WF_BYTES)                          // 5,578,752 B

__device__ __forceinline__ size_t fidx(int ktg, int nt, int lane) {
  return (((size_t)ktg * 16 + nt) * 64 + lane) * 8;
}

// ---------------- precompute: weights -> swizzled fp16 B-frags (r10-verified)
__global__ __launch_bounds__(256) void k_split_w16(
    const float* __restrict__ W1, const float* __restrict__ U1,
    const float* __restrict__ W2, const float* __restrict__ U2,
    f16* __restrict__ wf)
{
  int gid = blockIdx.x * 256 + threadIdx.x;           // one per (ktg,nt,lane)
  if (gid >= KT_ALL * 16 * 64) return;
  int lane = gid & 63, nt = (gid >> 6) & 15, ktg = gid >> 10;
  const float* M; int Kact, ktl;
  if (ktg < 4)       { M = W1; Kact = EMBD;  ktl = ktg;      }
  else if (ktg < 12) { M = U1; Kact = UNITS; ktl = ktg - 4;  }
  else if (ktg < 20) { M = W2; Kact = UNITS; ktl = ktg - 12; }
  else               { M = U2; Kact = UNITS; ktl = ktg - 20; }
  int n = nt * 16 + (lane & 15);
  int kb = ktl * 32 + (lane >> 4) * 8;
  size_t base = fidx(ktg, nt, lane);
#pragma unroll
  for (int j = 0; j < 8; ++j) {
    int k = kb + j;
    wf[base + j] = (f16)((k < Kact) ? M[(size_t)k * UNITS + n] : 0.f);  // RNE
  }
}

// ---------------- precompute: P1[v][n] = b1[n] + emb[v,:] @ W1 (f32 math) --
__global__ __launch_bounds__(256) void k_p1(
    const float* __restrict__ emb, const float* __restrict__ W1,
    const float* __restrict__ b1, f16* __restrict__ p1t)
{
  __shared__ float er[16][EMBD];
  const int v0 = blockIdx.x * 16;
  for (int i = threadIdx.x; i < 16 * EMBD; i += 256) {
    int vv = i / EMBD, kk = i - vv * EMBD;
    er[vv][kk] = emb[(size_t)(v0 + vv) * EMBD + kk];
  }
  __syncthreads();
  const int n = threadIdx.x;
  float acc[16];
  const float bb = b1[n];
#pragma unroll
  for (int vv = 0; vv < 16; ++vv) acc[vv] = bb;
  for (int k = 0; k < EMBD; ++k) {
    float w = W1[(size_t)k * UNITS + n];
#pragma unroll
    for (int vv = 0; vv < 16; ++vv) acc[vv] += er[vv][k] * w;
  }
#pragma unroll
  for (int vv = 0; vv < 16; ++vv)
    p1t[(size_t)(v0 + vv) * UNITS + n] = (f16)acc[vv];
}

#define MFMA16(A, B, C) __builtin_amdgcn_mfma_f32_16x16x32_f16(A, B, C, 0, 0, 0)

// store 4 consecutive-n f16 of the next-step A-frag in ONE b64 write.
// A-frag element (batch=m, k=n) lives at (n>>5)*512 + (((n>>3)&3)*16+m)*8
// + (n&7); for nb multiple of 4, the 4 targets are consecutive (8B-aligned).
__device__ __forceinline__ void store_row4(f16* __restrict__ f, int nb, int m,
                                           float v0, float v1, float v2, float v3) {
  int a = (nb >> 5) * 512 + (((nb >> 3) & 3) * 16 + m) * 8 + (nb & 7);
  h4 p; p[0] = (f16)v0; p[1] = (f16)v1; p[2] = (f16)v2; p[3] = (f16)v3;
  *(h4*)&f[a] = p;
}

#define P1S 264   // p1s row stride in f16: 528B; b64 reads ~4-way max

// ---------------------------------------------------------------------------
// Main kernel v17: 512 thr = 8 waves (2/SIMD), wave w owns n-tiles 2w, 2w+1.
// SWAPPED-OPERAND MFMA: D = MFMA(Wfrag, hfrag) = (h@W)^T; lane holds
// (n = tilebase + q*4 + r, batch = m). Iter i computes h1[i] and h2[i-1];
// one lgkm-only barrier/iter; compile-time buffer indices.
// Pinned: U1(a,b) W2(a,b) U2(a) = 160 regs.  U2(b): 64 KB dynamic LDS.
// ---------------------------------------------------------------------------
__global__ __launch_bounds__(512, 2)
__attribute__((amdgpu_waves_per_eu(2, 2)))
void rnn_wsD(
    const int* __restrict__ idx, const f16* __restrict__ p1t,
    const f16* __restrict__ wf, const float* __restrict__ b2,
    float* __restrict__ out)
{
  __shared__ __align__(16) f16 f1[2][4096];      // [buf][kt*512 + lane*8 + j]
  __shared__ __align__(16) f16 f2[2][4096];
  __shared__ __align__(16) f16 p1s[2][16 * P1S]; // [buf][row=batch][col=n]
  extern __shared__ f16 u2s[];                   // 64 KB: odd tiles of U2

  const int tid  = threadIdx.x;
  const int lane = tid & 63;
  const int w    = tid >> 6;          // wave 0..7 -> n-tiles 2w, 2w+1
  const int m    = lane & 15;         // batch row this lane accumulates
  const int q    = lane >> 4;
  const int b0   = blockIdx.x * 16;
  const int n0b  = 32 * w + 4 * q;    // 4-col group base, tile 2w
  const int n1b  = n0b + 16;          // tile 2w+1

  // bias: 4 consecutive n per tile (16B-aligned)
  const f32x4 b2v0 = *(const f32x4*)&b2[n0b];
  const f32x4 b2v1 = *(const f32x4*)&b2[n1b];

  // P1 staging assignment: thread covers 16B of row srow at offset spart*16B
  const int srow = tid >> 5, spart = tid & 31;
  const int* tokp = idx + (size_t)(b0 + srow) * TLEN;
  const f16* __restrict__ p1g = p1t + spart * 8;     // hoisted gather base

  // -------- stage U2 odd tiles into LDS (64 KB / 512 thr = 8 h8 each) -----
  for (int d = tid; d < 4096; d += 512) {        // d = (no*8+kt)*64 + l
    int l = d & 63, g = d >> 6, no = g >> 3, kt = g & 7;
    *(h8*)&u2s[(size_t)d * 8] = *(const h8*)(wf + fidx(20 + kt, 2 * no + 1, l));
  }

  // -------- persistent weight fragments: U1(a,b), W2(a,b), U2(a) -----------
  // (bytes unchanged: a W B-frag IS the A-frag of W^T)
  h8 Bu1a[8], Bu1b[8], Bw2a[8], Bw2b[8], Bu2a[8];
#pragma unroll
  for (int kt = 0; kt < 8; ++kt) {
    Bu1a[kt] = *(const h8*)(wf + fidx(4 + kt, 2 * w, lane));
    Bu1b[kt] = *(const h8*)(wf + fidx(4 + kt, 2 * w + 1, lane));
    Bw2a[kt] = *(const h8*)(wf + fidx(12 + kt, 2 * w, lane));
    Bw2b[kt] = *(const h8*)(wf + fidx(12 + kt, 2 * w + 1, lane));
    Bu2a[kt] = *(const h8*)(wf + fidx(20 + kt, 2 * w, lane));
  }
  // pin ("+v", proven spill-free at exactly this 160-reg footprint)
#pragma unroll
  for (int kt = 0; kt < 8; ++kt) {
    asm volatile("" : "+v"(Bu1a[kt])); asm volatile("" : "+v"(Bu1b[kt]));
    asm volatile("" : "+v"(Bw2a[kt])); asm volatile("" : "+v"(Bw2b[kt]));
    asm volatile("" : "+v"(Bu2a[kt]));
  }

  // -------- zero h2[-1] state (f2[0]); f1[0] fully written by the peel -----
  for (int i = tid; i < 4096; i += 512) f2[0][i] = (f16)0.f;

  // -------- peel i=0: h1[0] = tanh(P1[0]) — b64 gather, b64 frag write -----
  {
    int tk = idx[(size_t)(b0 + m) * TLEN + 0];
    const f16* pr = p1t + (size_t)tk * UNITS;
    h4 v0 = *(const h4*)(pr + n0b);
    h4 v1 = *(const h4*)(pr + n1b);
    store_row4(f1[0], n0b, m, fast_tanh((float)v0[0]), fast_tanh((float)v0[1]),
                              fast_tanh((float)v0[2]), fast_tanh((float)v0[3]));
    store_row4(f1[0], n1b, m, fast_tanh((float)v1[0]), fast_tanh((float)v1[1]),
                              fast_tanh((float)v1[2]), fast_tanh((float)v1[3]));
  }

  // -------- stage P1[1] into p1s[1]; prime token pipeline ------------------
  {
    int tk1 = tokp[1];
    h8 v = *(const h8*)(p1g + (size_t)tk1 * UNITS);
    *(h8*)&p1s[1][srow * P1S + spart * 8] = v;
  }
  int tkn = tokp[2];                   // token for iter1's stage of P1[2]
  __syncthreads();   // full barrier once: u2s, f2 zero, peel, p1s[1]

  // ======== one pipelined step; RD/WR are COMPILE-TIME 0/1 =================
  // Reads f1[RD], f2[RD], p1s[WR]; writes f1[WR], f2[WR], p1s[RD].
#define RNN_STEP(RD, WR, STAGE, TKI)                                         \
  {                                                                          \
    h8 p1v;                                                                  \
    if (STAGE) p1v = *(const h8*)(p1g + (size_t)tkn * UNITS);                \
    tkn = tokp[TKI];                                                         \
    h4 pA = *(const h4*)&p1s[WR][m * P1S + n0b];                             \
    h4 pB = *(const h4*)&p1s[WR][m * P1S + n1b];                             \
    f32x4 x0, x1;                                                            \
    _Pragma("unroll")                                                        \
    for (int r = 0; r < 4; ++r) {                                            \
      x0[r] = (float)pA[r];                                                  \
      x1[r] = (float)pB[r];                                                  \
    }                                                                        \
    f32x4 yA0 = b2v0, yA1 = b2v1;                                            \
    f32x4 yB0 = (f32x4){0.f, 0.f, 0.f, 0.f};                                 \
    f32x4 yB1 = (f32x4){0.f, 0.f, 0.f, 0.f};                                 \
    _Pragma("unroll")                                                        \
    for (int kt = 0; kt < 8; ++kt) {                                         \
      h8 a1 = *(const h8*)&f1[RD][kt * 512 + lane * 8];                      \
      h8 a2 = *(const h8*)&f2[RD][kt * 512 + lane * 8];                      \
      h8 ub = *(const h8*)&u2s[((w * 8 + kt) * 64 + lane) * 8];              \
      x0  = MFMA16(Bu1a[kt], a1, x0);                                        \
      x1  = MFMA16(Bu1b[kt], a1, x1);                                        \
      yA0 = MFMA16(Bw2a[kt], a1, yA0);                                       \
      yA1 = MFMA16(Bw2b[kt], a1, yA1);                                       \
      yB0 = MFMA16(Bu2a[kt], a2, yB0);                                       \
      yB1 = MFMA16(ub,       a2, yB1);                                       \
    }                                                                        \
    store_row4(f1[WR], n0b, m, fast_tanh(x0[0]), fast_tanh(x0[1]),           \
                               fast_tanh(x0[2]), fast_tanh(x0[3]));          \
    store_row4(f1[WR], n1b, m, fast_tanh(x1[0]), fast_tanh(x1[1]),           \
                               fast_tanh(x1[2]), fast_tanh(x1[3]));          \
    store_row4(f2[WR], n0b, m,                                               \
               fast_tanh(yA0[0] + yB0[0]), fast_tanh(yA0[1] + yB0[1]),       \
               fast_tanh(yA0[2] + yB0[2]), fast_tanh(yA0[3] + yB0[3]));      \
    store_row4(f2[WR], n1b, m,                                               \
               fast_tanh(yA1[0] + yB1[0]), fast_tanh(yA1[1] + yB1[1]),       \
               fast_tanh(yA1[2] + yB1[2]), fast_tanh(yA1[3] + yB1[3]));      \
    if (STAGE) *(h8*)&p1s[RD][srow * P1S + spart * 8] = p1v;                 \
    block_sync_lds();                                                        \
  }

  // -------- main loop: 39 pairs cover i = 1..78; i = 79 peeled -------------
  for (int i = 1; i < TLEN - 1; i += 2) {
    int t2 = i + 3 < TLEN - 1 ? i + 3 : TLEN - 1;   // clamp (last pair only)
    RNN_STEP(0, 1, true, i + 2);    // i odd:  reads buf0, writes buf1
    RNN_STEP(1, 0, true, t2);       // i+1:    reads buf1, writes buf0
  }
  RNN_STEP(0, 1, false, TLEN - 1);  // i = 79: no staging (tkn load harmless)
#undef RNN_STEP

  // -------- tail: h2[79] = tanh(b2 + h1[79]@W2 + h2[78]@U2) -> out ---------
  {
    f32x4 yA0 = b2v0, yA1 = b2v1;
    f32x4 yB0 = (f32x4){0.f, 0.f, 0.f, 0.f};
    f32x4 yB1 = (f32x4){0.f, 0.f, 0.f, 0.f};
#pragma unroll
    for (int kt = 0; kt < 8; ++kt) {
      h8 a1 = *(const h8*)&f1[1][kt * 512 + lane * 8];   // h1[79]
      h8 a2 = *(const h8*)&f2[1][kt * 512 + lane * 8];   // h2[78]
      h8 ub = *(const h8*)&u2s[((w * 8 + kt) * 64 + lane) * 8];
      yA0 = MFMA16(Bw2a[kt], a1, yA0);
      yA1 = MFMA16(Bw2b[kt], a1, yA1);
      yB0 = MFMA16(Bu2a[kt], a2, yB0);
      yB1 = MFMA16(ub,       a2, yB1);
    }
    f32x4 o0, o1;
#pragma unroll
    for (int r = 0; r < 4; ++r) {
      o0[r] = fast_sigmoid(fast_tanh(yA0[r] + yB0[r]));
      o1[r] = fast_sigmoid(fast_tanh(yA1[r] + yB1[r]));
    }
    *(f32x4*)&out[(size_t)(b0 + m) * UNITS + n0b] = o0;
    *(f32x4*)&out[(size_t)(b0 + m) * UNITS + n1b] = o1;
  }
}

// ---------------------------------------------------------------------------
extern "C" void kernel_launch(void* const* d_in, const int* in_sizes, int n_in,
                              void* d_out, int out_size, void* d_ws, size_t ws_size,
                              hipStream_t stream)
{
  const int*   idx = (const int*)d_in[0];
  const float* emb = (const float*)d_in[1];
  const float* W1  = (const float*)d_in[2];
  const float* U1  = (const float*)d_in[3];
  const float* b1  = (const float*)d_in[4];
  const float* W2  = (const float*)d_in[5];
  const float* U2  = (const float*)d_in[6];
  const float* b2  = (const float*)d_in[7];
  // d_in[8] (Wd), d_in[9] (bd) dead in the reference output.
  float* out = (float*)d_out;

  // 64 KB dynamic + ~48.5 KB static ≈ 114 KB LDS/workgroup -> 1 block/CU.
  static bool attr_done = false;
  if (!attr_done) {
    (void)hipFuncSetAttribute((const void*)rnn_wsD,
                              hipFuncAttributeMaxDynamicSharedMemorySize,
                              65536);
    attr_done = true;
  }

  f16* p1t = (f16*)((char*)d_ws + OFF_P1);
  f16* wf  = (f16*)((char*)d_ws + OFF_WF);
  k_p1<<<10000 / 16, 256, 0, stream>>>(emb, W1, b1, p1t);
  k_split_w16<<<(KT_ALL * 16 * 64 + 255) / 256, 256, 0, stream>>>(W1, U1, W2, U2, wf);
  rnn_wsD<<<BATCH / 16, 512, 65536, stream>>>(idx, p1t, wf, b2, out);
}